// Round 5
// baseline (50.829 us; speedup 1.0000x reference)
//
#include <hip/hip_runtime.h>

// Problem constants (from reference)
static constexpr int  B_  = 524288;
static constexpr int  K_  = 17;
static constexpr int  BK  = B_ * K_;            // 8912896 (b,k) pairs
static constexpr int  NTH = BK / 4;             // 2228224 threads, 4 pairs each
static constexpr long long OFF_Z   = (long long)BK * 2;  // floats (after gt_xy)
static constexpr long long OFF_IDX = OFF_Z + BK;         // floats (after gt_loc_z)

#define MAXXY 504.0f   // (64-1)*8.0
#define MAXZ  3.15f    // (64-1)*0.05

using v4f = __attribute__((ext_vector_type(4))) float;

// xorshift swizzle: bijective on [0,512); spreads the stride-2 xy write
// pattern across banks while keeping dense reads conflict-free.
__device__ __forceinline__ int swz(int e) { return e ^ (e >> 3); }

__global__ __launch_bounds__(256)
void kp_gt_kernel(const v4f* __restrict__ in4, float* __restrict__ out) {
    // lds_a: input tile (12 KB), then REUSED as the idx output tile.
    // Safe: thread t reads exactly entries {3t,3t+1,3t+2} and later writes
    // exactly those same entries — disjoint per-thread ownership, no race.
    __shared__ v4f lds_a[768];     // 12 KB
    __shared__ v4f lds_xy[512];    // 8 KB   (total 20 KB -> 8 blocks/CU)

    const int t   = threadIdx.x;
    const int blk = blockIdx.x;
    const int u   = blk * 256 + t;              // owns pairs 4u..4u+3
    const long long base = (long long)blk * 768;

    // ---- dense input loads: 3 instrs, each 64 lanes x 16B contiguous ----
    v4f a0 = in4[base + t];
    v4f a1 = in4[base + 256 + t];
    v4f a2 = in4[base + 512 + t];
    lds_a[t      ] = a0;
    lds_a[t + 256] = a1;
    lds_a[t + 512] = a2;
    __syncthreads();

    // ---- per-pair fetch from LDS: stride-3 v4f (measured conflict-free) ----
    const v4f v0 = lds_a[3 * t + 0];
    const v4f v1 = lds_a[3 * t + 1];
    const v4f v2 = lds_a[3 * t + 2];

    const float px[4] = {v0.x, v0.w, v1.z, v2.y};
    const float py[4] = {v0.y, v1.x, v1.w, v2.z};
    const float pz[4] = {v0.z, v1.y, v2.x, v2.w};

    float cx[4], cy[4], cz[4], fx[4], fy[4];
#pragma unroll
    for (int j = 0; j < 4; ++j) {
        cx[j] = fminf(fmaxf(px[j], 0.0f), MAXXY);
        cy[j] = fminf(fmaxf(py[j], 0.0f), MAXXY);
        cz[j] = fminf(fmaxf(pz[j], 0.0f), MAXZ);
        // *0.125f bit-exact vs /8.0f; non-negative after clip so (int) == astype(int32)
        fx[j] = (float)(int)(cx[j] * 0.125f);
        fy[j] = (float)(int)(cy[j] * 0.125f);
    }

    // batch index b = pair/17
    int p0 = 4 * u;
    int b0 = p0 / 17;
    int r  = p0 - b0 * 17;
    float fb[4];
#pragma unroll
    for (int j = 0; j < 4; ++j) {
        fb[j] = (float)b0;
        if (++r == 17) { r = 0; ++b0; }
    }

    // ---- z stream: per-thread dense, nt store ----
    {
        v4f w = {cz[0], cz[1], cz[2], cz[3]};
        __builtin_nontemporal_store(w, &((v4f*)(out + OFF_Z))[u]);
    }

    // ---- xy -> LDS (swizzled) ----
    lds_xy[swz(2 * t + 0)] = (v4f){cx[0], cy[0], cx[1], cy[1]};
    lds_xy[swz(2 * t + 1)] = (v4f){cx[2], cy[2], cx[3], cy[3]};

    // ---- idx -> lds_a (reuse; same entries this thread just read) ----
    {
        float tt[12];
#pragma unroll
        for (int j = 0; j < 4; ++j) {
            tt[3 * j + 0] = fb[j];
            tt[3 * j + 1] = fx[j];
            tt[3 * j + 2] = fy[j];
        }
        lds_a[3 * t + 0] = (v4f){tt[0], tt[1], tt[2],  tt[3]};
        lds_a[3 * t + 1] = (v4f){tt[4], tt[5], tt[6],  tt[7]};
        lds_a[3 * t + 2] = (v4f){tt[8], tt[9], tt[10], tt[11]};
    }

    __syncthreads();

    // ---- dense nt global stores: 64 lanes x 16B = contiguous 1KB/instr ----
    v4f* oxy = (v4f*)out;
    __builtin_nontemporal_store(lds_xy[swz(t)],       &oxy[(long long)blk * 512 + t]);
    __builtin_nontemporal_store(lds_xy[swz(t + 256)], &oxy[(long long)blk * 512 + 256 + t]);

    v4f* oi = (v4f*)(out + OFF_IDX);
    __builtin_nontemporal_store(lds_a[t      ], &oi[base + t]);
    __builtin_nontemporal_store(lds_a[t + 256], &oi[base + 256 + t]);
    __builtin_nontemporal_store(lds_a[t + 512], &oi[base + 512 + t]);
}

extern "C" void kernel_launch(void* const* d_in, const int* in_sizes, int n_in,
                              void* d_out, int out_size, void* d_ws, size_t ws_size,
                              hipStream_t stream) {
    const v4f* in4 = (const v4f*)d_in[0];
    float* out = (float*)d_out;
    const int block = 256;
    const int grid  = NTH / block;  // 8704 blocks, exact
    kp_gt_kernel<<<grid, block, 0, stream>>>(in4, out);
}